// Round 10
// baseline (201.702 us; speedup 1.0000x reference)
//
#include <hip/hip_runtime.h>

#define PI_D 3.14159265358979323846

// ---------------------------------------------------------------------------
// Compile-time twiddle tables: CT[k]=cos(2*pi*k/64), STb[k]=sin(2*pi*k/64).
// ---------------------------------------------------------------------------
namespace {
constexpr float CT[33] = {
  1.0000000000f,  0.9951847267f,  0.9807852804f,  0.9569403357f,
  0.9238795325f,  0.8819212643f,  0.8314696123f,  0.7730104534f,
  0.7071067812f,  0.6343932842f,  0.5555702330f,  0.4713967368f,
  0.3826834324f,  0.2902846773f,  0.1950903220f,  0.0980171403f,
  0.0f,          -0.0980171403f, -0.1950903220f, -0.2902846773f,
 -0.3826834324f, -0.4713967368f, -0.5555702330f, -0.6343932842f,
 -0.7071067812f, -0.7730104534f, -0.8314696123f, -0.8819212643f,
 -0.9238795325f, -0.9569403357f, -0.9807852804f, -0.9951847267f,
 -1.0f};
constexpr float STb[33] = {
  0.0f,           0.0980171403f,  0.1950903220f,  0.2902846773f,
  0.3826834324f,  0.4713967368f,  0.5555702330f,  0.6343932842f,
  0.7071067812f,  0.7730104534f,  0.8314696123f,  0.8819212643f,
  0.9238795325f,  0.9569403357f,  0.9807852804f,  0.9951847267f,
  1.0f,           0.9951847267f,  0.9807852804f,  0.9569403357f,
  0.9238795325f,  0.8819212643f,  0.8314696123f,  0.7730104534f,
  0.7071067812f,  0.6343932842f,  0.5555702330f,  0.4713967368f,
  0.3826834324f,  0.2902846773f,  0.1950903220f,  0.0980171403f,
  0.0f};
}

// STRAIGHT-LINE ONLY (R8/R10 lesson): no lane-conditional rewriting, all
// register indices compile-time. Branches below are on compile-time values.
__device__ __forceinline__ void bitrev64(float v[64]) {
#pragma unroll
  for (int i = 0; i < 64; ++i) {
    const int j = (int)(__brev((unsigned)i) >> 26);
    if (j > i) { const float tv = v[i]; v[i] = v[j]; v[j] = tv; }
  }
}

// Radix-2 DIT stages. ti==0 / ti==16 twiddles hand-folded (w=1, w=-+i):
// bit-identical to the mul form for finite inputs, ~24% fewer VALU ops.
// REAL=true (forward only): input purely real, im[] zero-initialized.
template <bool INV, bool REAL>
__device__ __forceinline__ void fft64_stages(float re[64], float im[64]) {
#pragma unroll
  for (int s = 0; s < 6; ++s) {
    const int half = 1 << s;
    const int m = half << 1;
    const int tstep = 32 >> s;
#pragma unroll
    for (int k = 0; k < 64; k += m) {
#pragma unroll
      for (int j = 0; j < half; ++j) {
        const int ti = j * tstep;
        const int a = k + j, b = k + j + half;
        if (REAL && j == 0) {          // w=1, both lanes real
          const float tr = re[b];
          re[b] = re[a] - tr;
          re[a] = re[a] + tr;
        } else if (REAL && ti == 16) { // forward w=-i, im[a]=im[b]=0 on entry
          const float t0 = re[b];
          re[b] = re[a];
          im[b] = t0;
          im[a] = -t0;
        } else {
          float tr, tii;
          if (ti == 0) {
            tr = re[b]; tii = im[b];
          } else if (ti == 16) {
            if (INV) { tr = -im[b]; tii = re[b]; }
            else     { tr =  im[b]; tii = -re[b]; }
          } else {
            const float wr = CT[ti];
            const float wi = INV ? STb[ti] : -STb[ti];
            tr  = re[b] * wr - im[b] * wi;
            tii = re[b] * wi + im[b] * wr;
          }
          re[b] = re[a] - tr;  im[b] = im[a] - tii;
          re[a] = re[a] + tr;  im[a] = im[a] + tii;
        }
      }
    }
  }
}

template <bool INV>
__device__ __forceinline__ void fft64_regs(float re[64], float im[64]) {
  bitrev64(re);
  bitrev64(im);
  fft64_stages<INV, false>(re, im);
}

// Forward FFT of a purely-real row; im[] must be all-zero on entry.
__device__ __forceinline__ void fft64_fwd_real(float re[64], float im[64]) {
  bitrev64(re);  // im all zero, no swaps needed
  fft64_stages<false, true>(re, im);
}

// Block-uniform frequency-band bounds straight from fbs (2 scalar loads).
__device__ __forceinline__ void band_from_fbs(const float* __restrict__ fbs,
                                              int c, int& s0, int& e0) {
  s0 = (int)floorf((fbs[2 * c]     + 1.0f) * 0.5f * 64.0f);
  e0 = (int)floorf((fbs[2 * c + 1] + 1.0f) * 0.5f * 64.0f);
}

// ---------------------------------------------------------------------------
// K1 (R20): fft MERGED with conv in one launch -- conv has no dependency on
// fft, is memory-bound, and overlaps fft's VALU-heavy blocks. Grid 5120
// x 64 threads: blk%5==4 -> conv group q5 in [0,1024) (4 rows SERIAL per
// wave: 12 accums, 6 row-loads/ch, zero-masked edge rows -- identical
// semantics to the 256-thread 4-row conv); else fft img = 4*q5 + r5.
// fft path: R19 Hermitian form (Mag rows {0} u [33,63] only; Fc complex
// for i<32; w1T fold in img==0).
// ---------------------------------------------------------------------------
__global__ __launch_bounds__(64) void k_fft_conv(
    const float* __restrict__ x, float* __restrict__ Mag,
    float* __restrict__ Fc, const float* __restrict__ fbs,
    const float* __restrict__ w1, float* __restrict__ w1T,
    const float* __restrict__ cw, const float* __restrict__ mixp,
    float* __restrict__ xsp, float* __restrict__ out) {
  __shared__ float buf[64][65];  // fft transpose buffer (conv blocks unused)
  const int t = threadIdx.x;
  const unsigned blk = blockIdx.x;
  const unsigned q5 = blk / 5u;
  const unsigned r5 = blk - q5 * 5u;

  if (r5 == 4u) {
    // ========= conv path: group q5 in [0,1024), rows r0..r0+3 serial =========
    const int lane = t;
    const int b = (int)(q5 >> 4);
    const int r0 = (int)((q5 & 15u) << 2);
    const float* xb = x + ((size_t)b << 18);
    const int rm = r0 > 0 ? r0 - 1 : 0;        // clamped load rows
    const int rp = r0 + 4 < 63 ? r0 + 4 : 63;
    const float m0 = (r0 > 0) ? 1.0f : 0.0f;       // zero-pad masks
    const float m5 = (r0 + 4 <= 63) ? 1.0f : 0.0f;
    float aL0 = 0.f, aM0 = 0.f, aR0 = 0.f;
    float aL1 = 0.f, aM1 = 0.f, aR1 = 0.f;
    float aL2 = 0.f, aM2 = 0.f, aR2 = 0.f;
    float aL3 = 0.f, aM3 = 0.f, aR3 = 0.f;
#pragma unroll 2
    for (int ch = 0; ch < 64; ++ch) {
      const float* xc = xb + (ch << 12);
      const float v0 = m0 * xc[(rm << 6) + lane];
      const float v1 = xc[((r0 + 0) << 6) + lane];
      const float v2 = xc[((r0 + 1) << 6) + lane];
      const float v3 = xc[((r0 + 2) << 6) + lane];
      const float v4 = xc[((r0 + 3) << 6) + lane];
      const float v5 = m5 * xc[(rp << 6) + lane];
      const float* wp = cw + ch * 9;  // block-uniform -> s_load via K$
      // output row q uses v[q], v[q+1], v[q+2] with vertical taps 0,1,2
      aL0 = fmaf(v0, wp[0], fmaf(v1, wp[3], fmaf(v2, wp[6], aL0)));
      aM0 = fmaf(v0, wp[1], fmaf(v1, wp[4], fmaf(v2, wp[7], aM0)));
      aR0 = fmaf(v0, wp[2], fmaf(v1, wp[5], fmaf(v2, wp[8], aR0)));
      aL1 = fmaf(v1, wp[0], fmaf(v2, wp[3], fmaf(v3, wp[6], aL1)));
      aM1 = fmaf(v1, wp[1], fmaf(v2, wp[4], fmaf(v3, wp[7], aM1)));
      aR1 = fmaf(v1, wp[2], fmaf(v2, wp[5], fmaf(v3, wp[8], aR1)));
      aL2 = fmaf(v2, wp[0], fmaf(v3, wp[3], fmaf(v4, wp[6], aL2)));
      aM2 = fmaf(v2, wp[1], fmaf(v3, wp[4], fmaf(v4, wp[7], aM2)));
      aR2 = fmaf(v2, wp[2], fmaf(v3, wp[5], fmaf(v4, wp[8], aR2)));
      aL3 = fmaf(v3, wp[0], fmaf(v4, wp[3], fmaf(v5, wp[6], aL3)));
      aM3 = fmaf(v3, wp[1], fmaf(v4, wp[4], fmaf(v5, wp[7], aM3)));
      aR3 = fmaf(v3, wp[2], fmaf(v4, wp[5], fmaf(v5, wp[8], aR3)));
    }
    const int b_s = (b + 32) & 63;
    int s0, e0;
    band_from_fbs(fbs, b_s, s0, e0);
    const float omix = 1.0f - mixp[0];
    float accQ[4];
    {
      const float QL[4] = {aL0, aL1, aL2, aL3};
      const float QM[4] = {aM0, aM1, aM2, aM3};
      const float QR[4] = {aR0, aR1, aR2, aR3};
#pragma unroll
      for (int q = 0; q < 4; ++q) {
        const float fromL = __shfl_up(QL[q], 1, 64);
        const float fromR = __shfl_down(QR[q], 1, 64);
        float acc = QM[q];
        if (lane > 0) acc += fromL;
        if (lane < 63) acc += fromR;
        accQ[q] = acc;
        xsp[((size_t)b << 12) + ((r0 + q) << 6) + lane] = acc;
      }
    }
    // Fused inactive-output epilogue (block-uniform per-i predicate).
#pragma unroll
    for (int q = 0; q < 4; ++q) {
      const float val = omix * accQ[q];
      float* ob = out + ((size_t)b << 18) + ((r0 + q) << 6) + lane;
#pragma unroll 4
      for (int i2 = 0; i2 < 64; ++i2) {
        const int i_s = (i2 + 32) & 63;
        if (!(i_s >= s0 && i_s < e0)) ob[(size_t)i2 << 12] = val;
      }
    }
    return;
  }

  // ================= fft path: img = 4*q5 + r5 in [0,4096) =================
  const int img = (int)(4u * q5 + r5);
  if (img == 0) {  // setup fold: w1T[c][k] = w1[k][c]
    for (int k = 0; k < 64; ++k) w1T[t * 64 + k] = w1[k * 64 + t];
  }
  const float* xp = x + ((size_t)img << 12);
  const float4* xr4 = reinterpret_cast<const float4*>(xp + (t << 6));
  float re[64], im[64];
#pragma unroll
  for (int q = 0; q < 16; ++q) {  // thread t = row t, per-lane 16B chunks
    const float4 v = xr4[q];
    re[4 * q]     = v.x; re[4 * q + 1] = v.y;
    re[4 * q + 2] = v.z; re[4 * q + 3] = v.w;
  }
#pragma unroll
  for (int j = 0; j < 64; ++j) im[j] = 0.0f;  // mostly DCE'd by REAL path
  fft64_fwd_real(re, im);  // row FFT
  // transpose, two passes through the single buffer (row-private writes)
#pragma unroll
  for (int j = 0; j < 64; ++j) buf[t][j] = re[j];
  __syncthreads();
#pragma unroll
  for (int j = 0; j < 64; ++j) re[j] = buf[j][t];
  __syncthreads();
#pragma unroll
  for (int j = 0; j < 64; ++j) buf[t][j] = im[j];
  __syncthreads();
#pragma unroll
  for (int j = 0; j < 64; ++j) im[j] = buf[j][t];
  fft64_regs<false>(re, im);  // column FFT; thread t now holds column t
  // magnitudes: ONLY unshifted rows {0} u [33,63] -- the exact set attn's
  // halved h-range consumes (u_f = (h+32)&63 for h in [1,32]).
  float* Mg = Mag + ((size_t)img << 12);
  Mg[t] = sqrtf(re[0] * re[0] + im[0] * im[0]);  // row 0 (h==32 / DC row)
#pragma unroll
  for (int j = 33; j < 64; ++j)
    Mg[j * 64 + t] = sqrtf(re[j] * re[j] + im[j] * im[j]);
  const int b = img >> 6, i = img & 63;
  const int b_s = (b + 32) & 63, i_s = (i + 32) & 63;
  int s0, e0;
  band_from_fbs(fbs, b_s, s0, e0);
  if ((i_s >= s0) && (i_s < e0)) {  // active: planar complex (block-uniform)
    // active => i_s in [32,64) => i in [0,32): slot fits the 2048-slot Fc
    float* Fre = Fc + ((size_t)((b << 5) + i) << 13);
    float* Fim = Fre + 4096;
#pragma unroll
    for (int j = 0; j < 64; ++j) {
      Fre[j * 64 + t] = re[j];
      Fim[j * 64 + t] = im[j];
    }
  }
}

// ---------------------------------------------------------------------------
// K2 (R20): attn-only, 2048 blocks x 256 threads (4-wave k-split).
// R19 had Occ 39%, VALUBusy 35% with conv mixed in (3072 blocks).
// R20: uniform blocks; __launch_bounds__(256,8) pins VGPR <= 64 so
// 8 blocks/CU = 32 waves/CU co-reside (2048 = 8 x 256 exactly).
// XCD-aware remap: the 32 blocks of one i-group share a 512KB Mag set;
// 8 groups/XCD = 4MB = one XCD L2. ai = (g<<5)|hh with g = (m>>5)*8+xcd,
// hh = m&31, m = bid>>3, xcd = bid&7 (bijective for 2048).
// Hermitian halving as R19: h in [1,32], mirror to Wc row 64-h.
// ---------------------------------------------------------------------------
__global__ __launch_bounds__(256, 8) void k_attn(
    const float* __restrict__ Mag, const float* __restrict__ w1T,
    const float* __restrict__ b1, const float* __restrict__ w2,
    const float* __restrict__ b2, const float* __restrict__ f0,
    const float* __restrict__ theta, const float* __restrict__ sigma,
    const float* __restrict__ theta0, const float* __restrict__ fbs,
    float* __restrict__ Wc) {
  __shared__ float part[4][3][64];  // partial logits (3KB)
  const int t = threadIdx.x;
  const unsigned bid = blockIdx.x;
  const unsigned m = bid >> 3, xcd = bid & 7u;
  const int ai = (int)(((((m >> 5) << 3) + xcd) << 5) | (m & 31u));
  const int lane = t & 63;                                   // = w
  const int wv = __builtin_amdgcn_readfirstlane(t >> 6);     // 0..3, SGPR
  const int k0 = wv << 4;                                    // k range base
  const int i = ai >> 5;                                     // attn channel
  const int h = (ai & 31) + 1;                               // row in [1,32]
  const int b_f = (i + 32) & 63;
  const int u_f = (h + 32) & 63;   // in {0} u [33,63] -- rows fft wrote
  const int v_f = (lane + 32) & 63;
  const int pos_f = (u_f << 6) + v_f;
  const float* Mb = Mag + (((size_t)(b_f << 6)) << 12) + pos_f;
  float acc[16];
#pragma unroll
  for (int k = 0; k < 16; ++k) acc[k] = 0.0f;
#pragma unroll 4
  for (int c = 0; c < 64; ++c) {
    const float mc = Mb[(size_t)((c + 32) & 63) << 12];
    const float* wrow = w1T + (c << 6) + k0;      // uniform -> s_load
#pragma unroll
    for (int k = 0; k < 16; ++k) acc[k] = fmaf(wrow[k], mc, acc[k]);
  }
  // partial logits over this wave's 16 hidden units
  float p0 = 0.0f, p1 = 0.0f, p2 = 0.0f;
#pragma unroll
  for (int k = 0; k < 16; ++k) {
    const float hv = fmaxf(acc[k] + b1[k0 + k], 0.0f);
    p0 = fmaf(w2[k0 + k], hv, p0);        // w2 layout [S=3][HID=64]
    p1 = fmaf(w2[64 + k0 + k], hv, p1);
    p2 = fmaf(w2[128 + k0 + k], hv, p2);
  }
  if (wv != 0) {
    part[wv][0][lane] = p0;
    part[wv][1][lane] = p1;
    part[wv][2][lane] = p2;
  }
  __syncthreads();
  if (wv != 0) return;  // uniform exit
  float l0 = b2[0] + p0 + part[1][0][lane] + part[2][0][lane] + part[3][0][lane];
  float l1 = b2[1] + p1 + part[1][1][lane] + part[2][1][lane] + part[3][1][lane];
  float l2 = b2[2] + p2 + part[1][2][lane] + part[2][2][lane] + part[3][2][lane];
  float mx = fmaxf(l0, fmaxf(l1, l2));
  float e0v = expf(l0 - mx), e1 = expf(l1 - mx), e2 = expf(l2 - mx);
  float inv = 1.0f / (e0v + e1 + e2);
  float aw0 = e0v * inv, aw1 = e1 * inv, aw2 = e2 * inv;
  // ---- Hermitian mirror: write Wc row hw = (h==32 ? 32 : 64-h) using
  // aw at (h, (64-lane)&63) (block-uniform branch; scalar shuffles only) ----
  int hw = h;
  if (h != 32) {
    const int src = (64 - lane) & 63;
    aw0 = __shfl(aw0, src, 64);
    aw1 = __shfl(aw1, src, 64);
    aw2 = __shfl(aw2, src, 64);
    hw = 64 - h;   // in [33,63]
  }
  const float yy = -1.0f + (float)hw * (2.0f / 63.0f);
  const float xx = -1.0f + (float)lane * (2.0f / 63.0f);
  const float r = sqrtf(xx * xx + yy * yy + 1e-6f);
  const float lr = logf(r);
  const float phi = atan2f(yy, xx);
  float wc = 0.0f;
  const float aws[3] = {aw0, aw1, aw2};
#pragma unroll
  for (int s = 0; s < 3; ++s) {
    const float f0v = f0[s * 64 + i];  // [S][O=1][I]
    const float sgv = sigma[s * 64 + i];
    const float thv = theta[s * 64 + i];
    const float t0v = theta0[s * 64 + i];
    const float ls = logf(sgv);
    const float d1 = lr - logf(f0v);
    const float g1 = expf(-(d1 * d1) / (2.0f * ls * ls));
    const float d2 = phi - thv;
    const float g2 = expf(-(d2 * d2) / (2.0f * t0v * t0v));
    wc = fmaf(g1 * g2, aws[s], wc);
  }
  Wc[((i << 6) + hw) * 64 + lane] = wc;
}

// ---------------------------------------------------------------------------
// K3 (unchanged from R19): ACTIVE images only; 2048 blocks (active requires
// i < 32). G = F*Wc*rowmask; IFFT2; real part; mix with conv path. Wc loads
// PREDICATED on the row mask (rows < 32 of Wc are never written).
// ---------------------------------------------------------------------------
__global__ __launch_bounds__(64) void k_ifft_act(
    const float* __restrict__ Fc, const float* __restrict__ Wc,
    const float* __restrict__ xsp, const float* __restrict__ fbs,
    const float* __restrict__ mixp, float* __restrict__ out) {
  const int b = blockIdx.x >> 5;
  const int i = blockIdx.x & 31;           // only i<32 can be active
  const int b_s = (b + 32) & 63, i_s = i + 32;
  int s0, e0;
  band_from_fbs(fbs, b_s, s0, e0);
  if (!((i_s >= s0) && (i_s < e0))) return;  // inactive: handled by conv path
  __shared__ float buf[64][65];
  const int t = threadIdx.x;
  const float* Fre = Fc + ((size_t)((b << 5) + i) << 13);
  const float* Fim = Fre + 4096;
  const float* Wcp = Wc + ((size_t)i_s << 12);
  // Thread t owns row t: value = F[t][j] * rowmask(u_s(t)) * Wc[u_s][v_s(j)].
  const int u_s = (t + 32) & 63;
  const bool act_row = (u_s >= s0 && u_s < e0);  // rows in [32,64) only
  const float* wrow = Wcp + (u_s << 6);
  const float4* fr4 = reinterpret_cast<const float4*>(Fre + (t << 6));
  const float4* fi4 = reinterpret_cast<const float4*>(Fim + (t << 6));
  float re[64], im[64];
#pragma unroll
  for (int q = 0; q < 16; ++q) {
    const int j0 = 4 * q;
    // v_s = (j+32)&63: compile-time offset per q (wraps at q==8)
    const float4 w4 = act_row
        ? *reinterpret_cast<const float4*>(wrow + ((j0 + 32) & 63))
        : make_float4(0.0f, 0.0f, 0.0f, 0.0f);
    const float4 vr = fr4[q];
    const float4 vi = fi4[q];
    re[j0]     = vr.x * w4.x;  re[j0 + 1] = vr.y * w4.y;
    re[j0 + 2] = vr.z * w4.z;  re[j0 + 3] = vr.w * w4.w;
    im[j0]     = vi.x * w4.x;  im[j0 + 1] = vi.y * w4.y;
    im[j0 + 2] = vi.z * w4.z;  im[j0 + 3] = vi.w * w4.w;
  }
  fft64_regs<true>(re, im);  // row inverse FFTs
  // transpose (two passes)
#pragma unroll
  for (int j = 0; j < 64; ++j) buf[t][j] = re[j];
  __syncthreads();
#pragma unroll
  for (int j = 0; j < 64; ++j) re[j] = buf[j][t];
  __syncthreads();
#pragma unroll
  for (int j = 0; j < 64; ++j) buf[t][j] = im[j];
  __syncthreads();
#pragma unroll
  for (int j = 0; j < 64; ++j) im[j] = buf[j][t];
  fft64_regs<true>(re, im);  // column inverse FFTs; thread t holds column t
  const float mixv = mixp[0];
  const float sc = mixv * (1.0f / 4096.0f);
  const float om = 1.0f - mixv;
  float* op = out + (((size_t)(b << 6) + i) << 12);
  const float* xp = xsp + ((size_t)b << 12);
#pragma unroll
  for (int j = 0; j < 64; ++j)
    op[j * 64 + t] = fmaf(sc, re[j], om * xp[j * 64 + t]);
}

// ---------------------------------------------------------------------------
// Workspace layout (~130.3 MB):
//   [0, 64MB)          Mag  float[4096][4096]  (only unshifted rows
//                                              {0} u [33,63] written/read)
//   [+64MB, +128MB)    Fc   2048 slots x 32KB  {Fre,Fim} for i<32 images
//   [+128MB, +129MB)   Wc   float[64*64*64]    (only rows 32..63 written)
//   [+129MB, +130MB)   xsp  float[64*64*64]
//   [+130MB, ..)       w1T  float[64*64]   (written by k_fft_conv img 0)
// ---------------------------------------------------------------------------
extern "C" void kernel_launch(void* const* d_in, const int* in_sizes, int n_in,
                              void* d_out, int out_size, void* d_ws, size_t ws_size,
                              hipStream_t stream) {
  const float* x      = (const float*)d_in[0];
  const float* f0     = (const float*)d_in[1];
  const float* theta  = (const float*)d_in[2];
  const float* sigma  = (const float*)d_in[3];
  const float* theta0 = (const float*)d_in[4];
  const float* fbs    = (const float*)d_in[5];
  const float* mix    = (const float*)d_in[6];
  const float* w1     = (const float*)d_in[7];
  const float* b1     = (const float*)d_in[8];
  const float* w2     = (const float*)d_in[9];
  const float* b2     = (const float*)d_in[10];
  const float* cw     = (const float*)d_in[11];
  float* out = (float*)d_out;
  char* ws = (char*)d_ws;
  float* Mag = (float*)(ws);
  float* Fc  = (float*)(ws + 67108864);
  float* Wc  = (float*)(ws + 134217728);
  float* xsp = (float*)(ws + 134217728 + 1048576);
  float* w1T = (float*)(ws + 134217728 + 2097152);

  k_fft_conv<<<5120, 64, 0, stream>>>(x, Mag, Fc, fbs, w1, w1T, cw, mix,
                                      xsp, out);
  k_attn<<<2048, 256, 0, stream>>>(Mag, w1T, b1, w2, b2, f0, theta, sigma,
                                   theta0, fbs, Wc);
  k_ifft_act<<<2048, 64, 0, stream>>>(Fc, Wc, xsp, fbs, mix, out);
}

// Round 11
// 189.277 us; speedup vs baseline: 1.0656x; 1.0656x over previous
//
#include <hip/hip_runtime.h>

#define PI_D 3.14159265358979323846

// ---------------------------------------------------------------------------
// Compile-time twiddle tables: CT[k]=cos(2*pi*k/64), STb[k]=sin(2*pi*k/64).
// ---------------------------------------------------------------------------
namespace {
constexpr float CT[33] = {
  1.0000000000f,  0.9951847267f,  0.9807852804f,  0.9569403357f,
  0.9238795325f,  0.8819212643f,  0.8314696123f,  0.7730104534f,
  0.7071067812f,  0.6343932842f,  0.5555702330f,  0.4713967368f,
  0.3826834324f,  0.2902846773f,  0.1950903220f,  0.0980171403f,
  0.0f,          -0.0980171403f, -0.1950903220f, -0.2902846773f,
 -0.3826834324f, -0.4713967368f, -0.5555702330f, -0.6343932842f,
 -0.7071067812f, -0.7730104534f, -0.8314696123f, -0.8819212643f,
 -0.9238795325f, -0.9569403357f, -0.9807852804f, -0.9951847267f,
 -1.0f};
constexpr float STb[33] = {
  0.0f,           0.0980171403f,  0.1950903220f,  0.2902846773f,
  0.3826834324f,  0.4713967368f,  0.5555702330f,  0.6343932842f,
  0.7071067812f,  0.7730104534f,  0.8314696123f,  0.8819212643f,
  0.9238795325f,  0.9569403357f,  0.9807852804f,  0.9951847267f,
  1.0f,           0.9951847267f,  0.9807852804f,  0.9569403357f,
  0.9238795325f,  0.8819212643f,  0.8314696123f,  0.7730104534f,
  0.7071067812f,  0.6343932842f,  0.5555702330f,  0.4713967368f,
  0.3826834324f,  0.2902846773f,  0.1950903220f,  0.0980171403f,
  0.0f};
}

// STRAIGHT-LINE ONLY (R8/R10 lesson): no lane-conditional rewriting, all
// register indices compile-time. Branches below are on compile-time values.
__device__ __forceinline__ void bitrev64(float v[64]) {
#pragma unroll
  for (int i = 0; i < 64; ++i) {
    const int j = (int)(__brev((unsigned)i) >> 26);
    if (j > i) { const float tv = v[i]; v[i] = v[j]; v[j] = tv; }
  }
}

// Radix-2 DIT stages. ti==0 / ti==16 twiddles hand-folded (w=1, w=-+i):
// bit-identical to the mul form for finite inputs, ~24% fewer VALU ops.
// REAL=true (forward only): input purely real, im[] zero-initialized.
template <bool INV, bool REAL>
__device__ __forceinline__ void fft64_stages(float re[64], float im[64]) {
#pragma unroll
  for (int s = 0; s < 6; ++s) {
    const int half = 1 << s;
    const int m = half << 1;
    const int tstep = 32 >> s;
#pragma unroll
    for (int k = 0; k < 64; k += m) {
#pragma unroll
      for (int j = 0; j < half; ++j) {
        const int ti = j * tstep;
        const int a = k + j, b = k + j + half;
        if (REAL && j == 0) {          // w=1, both lanes real
          const float tr = re[b];
          re[b] = re[a] - tr;
          re[a] = re[a] + tr;
        } else if (REAL && ti == 16) { // forward w=-i, im[a]=im[b]=0 on entry
          const float t0 = re[b];
          re[b] = re[a];
          im[b] = t0;
          im[a] = -t0;
        } else {
          float tr, tii;
          if (ti == 0) {
            tr = re[b]; tii = im[b];
          } else if (ti == 16) {
            if (INV) { tr = -im[b]; tii = re[b]; }
            else     { tr =  im[b]; tii = -re[b]; }
          } else {
            const float wr = CT[ti];
            const float wi = INV ? STb[ti] : -STb[ti];
            tr  = re[b] * wr - im[b] * wi;
            tii = re[b] * wi + im[b] * wr;
          }
          re[b] = re[a] - tr;  im[b] = im[a] - tii;
          re[a] = re[a] + tr;  im[a] = im[a] + tii;
        }
      }
    }
  }
}

template <bool INV>
__device__ __forceinline__ void fft64_regs(float re[64], float im[64]) {
  bitrev64(re);
  bitrev64(im);
  fft64_stages<INV, false>(re, im);
}

// Forward FFT of a purely-real row; im[] must be all-zero on entry.
__device__ __forceinline__ void fft64_fwd_real(float re[64], float im[64]) {
  bitrev64(re);  // im all zero, no swaps needed
  fft64_stages<false, true>(re, im);
}

// Block-uniform frequency-band bounds straight from fbs (2 scalar loads).
__device__ __forceinline__ void band_from_fbs(const float* __restrict__ fbs,
                                              int c, int& s0, int& e0) {
  s0 = (int)floorf((fbs[2 * c]     + 1.0f) * 0.5f * 64.0f);
  e0 = (int)floorf((fbs[2 * c + 1] + 1.0f) * 0.5f * 64.0f);
}

// ---------------------------------------------------------------------------
// K1 (R21): forward FFT2, one image per wave-block. R20's conv merge
// REVERTED (conv blocks inherited fft's 16.9KB LDS -> 13% occupancy).
// NEW: HERMITIAN-COLUMN TRANSPOSE. Row FFT of a REAL row is Hermitian in
// the column index: X[j][64-c] = conj(X[j][c]) -- only columns 0..32 are
// independent. Buffer shrinks to [64][33] (8448B, was 16.9KB): each
// thread stores cols 0..32 of its row; thread t reads column
// ct = (t<=32 ? t : 64-t) and negates im for t>32 (the values loaded ARE
// column t), so the column FFT and all stores are unchanged. Reads by
// lane pairs (t, 64-t) hit the same address -> broadcast, conflict-free.
// LDS occupancy cap: 9 -> 18 blocks/CU (VGPR 120 then caps ~16 waves/CU).
// Mag rows {0} u [33,63] only; Fc complex for i<32; w1T fold in img==0.
// ---------------------------------------------------------------------------
__global__ __launch_bounds__(64) void k_fft_fwd(const float* __restrict__ x,
                                                float* __restrict__ Mag,
                                                float* __restrict__ Fc,
                                                const float* __restrict__ fbs,
                                                const float* __restrict__ w1,
                                                float* __restrict__ w1T) {
  __shared__ float buf[64][33];  // 8448B: Hermitian half-transpose buffer
  const int t = threadIdx.x;
  const int img = blockIdx.x;
  if (img == 0) {  // setup fold: w1T[c][k] = w1[k][c]
    for (int k = 0; k < 64; ++k) w1T[t * 64 + k] = w1[k * 64 + t];
  }
  const float* xp = x + ((size_t)img << 12);
  const float4* xr4 = reinterpret_cast<const float4*>(xp + (t << 6));
  float re[64], im[64];
#pragma unroll
  for (int q = 0; q < 16; ++q) {  // thread t = row t, per-lane 16B chunks
    const float4 v = xr4[q];
    re[4 * q]     = v.x; re[4 * q + 1] = v.y;
    re[4 * q + 2] = v.z; re[4 * q + 3] = v.w;
  }
#pragma unroll
  for (int j = 0; j < 64; ++j) im[j] = 0.0f;  // mostly DCE'd by REAL path
  fft64_fwd_real(re, im);  // row FFT (rows real => row-Hermitian output)
  // Hermitian-column transpose: store cols 0..32 only; read col ct.
  const int ct = (t <= 32) ? t : 64 - t;
  const float isgn = (t <= 32) ? 1.0f : -1.0f;
#pragma unroll
  for (int j = 0; j <= 32; ++j) buf[t][j] = re[j];
  __syncthreads();
#pragma unroll
  for (int j = 0; j < 64; ++j) re[j] = buf[j][ct];
  __syncthreads();
#pragma unroll
  for (int j = 0; j <= 32; ++j) buf[t][j] = im[j];
  __syncthreads();
#pragma unroll
  for (int j = 0; j < 64; ++j) im[j] = isgn * buf[j][ct];
  fft64_regs<false>(re, im);  // column FFT; thread t now holds column t
  // magnitudes: ONLY unshifted rows {0} u [33,63] -- the exact set attn's
  // halved h-range consumes (u_f = (h+32)&63 for h in [1,32]).
  float* Mg = Mag + ((size_t)img << 12);
  Mg[t] = sqrtf(re[0] * re[0] + im[0] * im[0]);  // row 0 (h==32 / DC row)
#pragma unroll
  for (int j = 33; j < 64; ++j)
    Mg[j * 64 + t] = sqrtf(re[j] * re[j] + im[j] * im[j]);
  const int b = img >> 6, i = img & 63;
  const int b_s = (b + 32) & 63, i_s = (i + 32) & 63;
  int s0, e0;
  band_from_fbs(fbs, b_s, s0, e0);
  if ((i_s >= s0) && (i_s < e0)) {  // active: planar complex (block-uniform)
    // active => i_s in [32,64) => i in [0,32): slot fits the 2048-slot Fc
    float* Fre = Fc + ((size_t)((b << 5) + i) << 13);
    float* Fim = Fre + 4096;
#pragma unroll
    for (int j = 0; j < 64; ++j) {
      Fre[j * 64 + t] = re[j];
      Fim[j * 64 + t] = im[j];
    }
  }
}

// ---------------------------------------------------------------------------
// K2 (R21 = R19 verbatim): attn+conv merged, 256-thread / 4-wave blocks,
// k-split attn. Hermitian halving: attn runs h in [1,32] only (2048
// tasks); mirror via __shfl to Wc row 64-h. Conv 4 rows/block. Grid 3072,
// blk%3==2 -> conv. (R20 taught: merge only footprint-compatible paths --
// attn and conv are both ~3KB LDS / ~28 VGPR.)
// ---------------------------------------------------------------------------
__global__ __launch_bounds__(256, 4) void k_attn_conv(
    const float* __restrict__ Mag, const float* __restrict__ w1T,
    const float* __restrict__ b1, const float* __restrict__ w2,
    const float* __restrict__ b2, const float* __restrict__ f0,
    const float* __restrict__ theta, const float* __restrict__ sigma,
    const float* __restrict__ theta0, const float* __restrict__ fbs,
    float* __restrict__ Wc,
    const float* __restrict__ x, const float* __restrict__ cw,
    const float* __restrict__ mixp, float* __restrict__ xsp,
    float* __restrict__ out) {
  __shared__ float part[4][3][64];  // attn partial logits (3KB; conv unused)
  const int t = threadIdx.x;
  const unsigned blk = blockIdx.x;
  const unsigned q3 = blk / 3u;
  const unsigned r3 = blk - q3 * 3u;

  if (r3 == 2u) {
    // ============ conv path (cb = q3 in [0,1024), 4 rows/block) ============
    const int lane = t & 63;
    const int cwv = t >> 6;                     // 0..3
    const int b = (int)(q3 >> 4);
    const int row = (int)((q3 & 15u) << 2) | cwv;
    const float* xb = x + ((size_t)b << 18);
    const int rm = row > 0 ? row - 1 : 0;  // clamped (masked in epilogue)
    const int rp = row < 63 ? row + 1 : 63;
    float P00 = 0.f, P01 = 0.f, P02 = 0.f;
    float P10 = 0.f, P11 = 0.f, P12 = 0.f;
    float P20 = 0.f, P21 = 0.f, P22 = 0.f;
#pragma unroll 4
    for (int ch = 0; ch < 64; ++ch) {
      const float* xc = xb + (ch << 12);
      const float v0 = xc[(rm << 6) + lane];
      const float v1 = xc[(row << 6) + lane];
      const float v2 = xc[(rp << 6) + lane];
      const float* wp = cw + ch * 9;  // block-uniform -> s_load via K$
      P00 = fmaf(v0, wp[0], P00);
      P01 = fmaf(v0, wp[1], P01);
      P02 = fmaf(v0, wp[2], P02);
      P10 = fmaf(v1, wp[3], P10);
      P11 = fmaf(v1, wp[4], P11);
      P12 = fmaf(v1, wp[5], P12);
      P20 = fmaf(v2, wp[6], P20);
      P21 = fmaf(v2, wp[7], P21);
      P22 = fmaf(v2, wp[8], P22);
    }
    const float tmask = (row > 0) ? 1.0f : 0.0f;
    const float bmask = (row < 63) ? 1.0f : 0.0f;
    const float Ql = tmask * P00 + P10 + bmask * P20;
    const float Qm = tmask * P01 + P11 + bmask * P21;
    const float Qr = tmask * P02 + P12 + bmask * P22;
    const float fromL = __shfl_up(Ql, 1, 64);
    const float fromR = __shfl_down(Qr, 1, 64);
    float acc = Qm;
    if (lane > 0) acc += fromL;
    if (lane < 63) acc += fromR;
    xsp[((size_t)b << 12) + (row << 6) + lane] = acc;
    // Fused inactive-output epilogue (block-uniform per-i predicate).
    const int b_s = (b + 32) & 63;
    int s0, e0;
    band_from_fbs(fbs, b_s, s0, e0);
    const float val = (1.0f - mixp[0]) * acc;
    float* ob = out + ((size_t)b << 18) + (row << 6) + lane;
#pragma unroll 4
    for (int i2 = 0; i2 < 64; ++i2) {
      const int i_s = (i2 + 32) & 63;
      if (!(i_s >= s0 && i_s < e0)) ob[(size_t)i2 << 12] = val;
    }
    return;
  }

  // ===== attn path: ai = 2*q3 + r3 in [0,2048); i = ai>>5, h = (ai&31)+1 =====
  const int ai = (int)(2u * q3 + r3);
  const int lane = t & 63;                                   // = w
  const int wv = __builtin_amdgcn_readfirstlane(t >> 6);     // 0..3, SGPR
  const int k0 = wv << 4;                                    // k range base
  const int i = ai >> 5;                                     // attn channel
  const int h = (ai & 31) + 1;                               // row in [1,32]
  const int b_f = (i + 32) & 63;
  const int u_f = (h + 32) & 63;   // in {0} u [33,63] -- rows fft wrote
  const int v_f = (lane + 32) & 63;
  const int pos_f = (u_f << 6) + v_f;
  const float* Mb = Mag + (((size_t)(b_f << 6)) << 12) + pos_f;
  float acc[16];
#pragma unroll
  for (int k = 0; k < 16; ++k) acc[k] = 0.0f;
#pragma unroll 4
  for (int c = 0; c < 64; ++c) {
    const float mc = Mb[(size_t)((c + 32) & 63) << 12];
    const float* wrow = w1T + (c << 6) + k0;      // uniform -> s_load
#pragma unroll
    for (int k = 0; k < 16; ++k) acc[k] = fmaf(wrow[k], mc, acc[k]);
  }
  // partial logits over this wave's 16 hidden units
  float p0 = 0.0f, p1 = 0.0f, p2 = 0.0f;
#pragma unroll
  for (int k = 0; k < 16; ++k) {
    const float hv = fmaxf(acc[k] + b1[k0 + k], 0.0f);
    p0 = fmaf(w2[k0 + k], hv, p0);        // w2 layout [S=3][HID=64]
    p1 = fmaf(w2[64 + k0 + k], hv, p1);
    p2 = fmaf(w2[128 + k0 + k], hv, p2);
  }
  if (wv != 0) {
    part[wv][0][lane] = p0;
    part[wv][1][lane] = p1;
    part[wv][2][lane] = p2;
  }
  __syncthreads();
  if (wv != 0) return;  // uniform exit
  float l0 = b2[0] + p0 + part[1][0][lane] + part[2][0][lane] + part[3][0][lane];
  float l1 = b2[1] + p1 + part[1][1][lane] + part[2][1][lane] + part[3][1][lane];
  float l2 = b2[2] + p2 + part[1][2][lane] + part[2][2][lane] + part[3][2][lane];
  float mx = fmaxf(l0, fmaxf(l1, l2));
  float e0v = expf(l0 - mx), e1 = expf(l1 - mx), e2 = expf(l2 - mx);
  float inv = 1.0f / (e0v + e1 + e2);
  float aw0 = e0v * inv, aw1 = e1 * inv, aw2 = e2 * inv;
  // ---- Hermitian mirror: write Wc row hw = (h==32 ? 32 : 64-h) using
  // aw at (h, (64-lane)&63) (block-uniform branch; scalar shuffles only) ----
  int hw = h;
  if (h != 32) {
    const int src = (64 - lane) & 63;
    aw0 = __shfl(aw0, src, 64);
    aw1 = __shfl(aw1, src, 64);
    aw2 = __shfl(aw2, src, 64);
    hw = 64 - h;   // in [33,63]
  }
  const float yy = -1.0f + (float)hw * (2.0f / 63.0f);
  const float xx = -1.0f + (float)lane * (2.0f / 63.0f);
  const float r = sqrtf(xx * xx + yy * yy + 1e-6f);
  const float lr = logf(r);
  const float phi = atan2f(yy, xx);
  float wc = 0.0f;
  const float aws[3] = {aw0, aw1, aw2};
#pragma unroll
  for (int s = 0; s < 3; ++s) {
    const float f0v = f0[s * 64 + i];  // [S][O=1][I]
    const float sgv = sigma[s * 64 + i];
    const float thv = theta[s * 64 + i];
    const float t0v = theta0[s * 64 + i];
    const float ls = logf(sgv);
    const float d1 = lr - logf(f0v);
    const float g1 = expf(-(d1 * d1) / (2.0f * ls * ls));
    const float d2 = phi - thv;
    const float g2 = expf(-(d2 * d2) / (2.0f * t0v * t0v));
    wc = fmaf(g1 * g2, aws[s], wc);
  }
  Wc[((i << 6) + hw) * 64 + lane] = wc;
}

// ---------------------------------------------------------------------------
// K3 (unchanged from R19): ACTIVE images only; 2048 blocks (active requires
// i < 32). G = F*Wc*rowmask; IFFT2; real part; mix with conv path. Wc loads
// PREDICATED on the row mask (rows < 32 of Wc are never written). Input to
// the inverse FFT is NOT Hermitian (Wc breaks symmetry) -> full [64][65]
// transpose buffer stays.
// ---------------------------------------------------------------------------
__global__ __launch_bounds__(64) void k_ifft_act(
    const float* __restrict__ Fc, const float* __restrict__ Wc,
    const float* __restrict__ xsp, const float* __restrict__ fbs,
    const float* __restrict__ mixp, float* __restrict__ out) {
  const int b = blockIdx.x >> 5;
  const int i = blockIdx.x & 31;           // only i<32 can be active
  const int b_s = (b + 32) & 63, i_s = i + 32;
  int s0, e0;
  band_from_fbs(fbs, b_s, s0, e0);
  if (!((i_s >= s0) && (i_s < e0))) return;  // inactive: handled by conv path
  __shared__ float buf[64][65];
  const int t = threadIdx.x;
  const float* Fre = Fc + ((size_t)((b << 5) + i) << 13);
  const float* Fim = Fre + 4096;
  const float* Wcp = Wc + ((size_t)i_s << 12);
  // Thread t owns row t: value = F[t][j] * rowmask(u_s(t)) * Wc[u_s][v_s(j)].
  const int u_s = (t + 32) & 63;
  const bool act_row = (u_s >= s0 && u_s < e0);  // rows in [32,64) only
  const float* wrow = Wcp + (u_s << 6);
  const float4* fr4 = reinterpret_cast<const float4*>(Fre + (t << 6));
  const float4* fi4 = reinterpret_cast<const float4*>(Fim + (t << 6));
  float re[64], im[64];
#pragma unroll
  for (int q = 0; q < 16; ++q) {
    const int j0 = 4 * q;
    // v_s = (j+32)&63: compile-time offset per q (wraps at q==8)
    const float4 w4 = act_row
        ? *reinterpret_cast<const float4*>(wrow + ((j0 + 32) & 63))
        : make_float4(0.0f, 0.0f, 0.0f, 0.0f);
    const float4 vr = fr4[q];
    const float4 vi = fi4[q];
    re[j0]     = vr.x * w4.x;  re[j0 + 1] = vr.y * w4.y;
    re[j0 + 2] = vr.z * w4.z;  re[j0 + 3] = vr.w * w4.w;
    im[j0]     = vi.x * w4.x;  im[j0 + 1] = vi.y * w4.y;
    im[j0 + 2] = vi.z * w4.z;  im[j0 + 3] = vi.w * w4.w;
  }
  fft64_regs<true>(re, im);  // row inverse FFTs
  // transpose (two passes)
#pragma unroll
  for (int j = 0; j < 64; ++j) buf[t][j] = re[j];
  __syncthreads();
#pragma unroll
  for (int j = 0; j < 64; ++j) re[j] = buf[j][t];
  __syncthreads();
#pragma unroll
  for (int j = 0; j < 64; ++j) buf[t][j] = im[j];
  __syncthreads();
#pragma unroll
  for (int j = 0; j < 64; ++j) im[j] = buf[j][t];
  fft64_regs<true>(re, im);  // column inverse FFTs; thread t holds column t
  const float mixv = mixp[0];
  const float sc = mixv * (1.0f / 4096.0f);
  const float om = 1.0f - mixv;
  float* op = out + (((size_t)(b << 6) + i) << 12);
  const float* xp = xsp + ((size_t)b << 12);
#pragma unroll
  for (int j = 0; j < 64; ++j)
    op[j * 64 + t] = fmaf(sc, re[j], om * xp[j * 64 + t]);
}

// ---------------------------------------------------------------------------
// Workspace layout (~130.3 MB):
//   [0, 64MB)          Mag  float[4096][4096]  (only unshifted rows
//                                              {0} u [33,63] written/read)
//   [+64MB, +128MB)    Fc   2048 slots x 32KB  {Fre,Fim} for i<32 images
//   [+128MB, +129MB)   Wc   float[64*64*64]    (only rows 32..63 written)
//   [+129MB, +130MB)   xsp  float[64*64*64]
//   [+130MB, ..)       w1T  float[64*64]   (written by k_fft_fwd img 0)
// ---------------------------------------------------------------------------
extern "C" void kernel_launch(void* const* d_in, const int* in_sizes, int n_in,
                              void* d_out, int out_size, void* d_ws, size_t ws_size,
                              hipStream_t stream) {
  const float* x      = (const float*)d_in[0];
  const float* f0     = (const float*)d_in[1];
  const float* theta  = (const float*)d_in[2];
  const float* sigma  = (const float*)d_in[3];
  const float* theta0 = (const float*)d_in[4];
  const float* fbs    = (const float*)d_in[5];
  const float* mix    = (const float*)d_in[6];
  const float* w1     = (const float*)d_in[7];
  const float* b1     = (const float*)d_in[8];
  const float* w2     = (const float*)d_in[9];
  const float* b2     = (const float*)d_in[10];
  const float* cw     = (const float*)d_in[11];
  float* out = (float*)d_out;
  char* ws = (char*)d_ws;
  float* Mag = (float*)(ws);
  float* Fc  = (float*)(ws + 67108864);
  float* Wc  = (float*)(ws + 134217728);
  float* xsp = (float*)(ws + 134217728 + 1048576);
  float* w1T = (float*)(ws + 134217728 + 2097152);

  k_fft_fwd<<<4096, 64, 0, stream>>>(x, Mag, Fc, fbs, w1, w1T);
  k_attn_conv<<<3072, 256, 0, stream>>>(Mag, w1T, b1, w2, b2, f0, theta, sigma,
                                        theta0, fbs, Wc, x, cw, mix, xsp, out);
  k_ifft_act<<<2048, 64, 0, stream>>>(Fc, Wc, xsp, fbs, mix, out);
}